// Round 1
// baseline (168.174 us; speedup 1.0000x reference)
//
#include <hip/hip_runtime.h>
#include <hip/hip_bf16.h>

// Bi-attention: q1=x@w1^T+b1, q2=y_tok@w2^T+b2, S=softmax(q1 q2^T/8) rowwise,
// v2 = S q2 (out0, (B,N,D)), v1 = S^T q1 written as (B,D,H*W) (out1).
// B=4, N1=N2=4096, D=64. All heavy math in bf16 MFMA 16x16x32, fp32 accum.

typedef __attribute__((ext_vector_type(8))) short s8v;   // 8 x bf16 frag
typedef __attribute__((ext_vector_type(4))) float f4v;   // 4 x f32 acc

constexpr int B = 4, N = 4096, D = 64, SPLIT = 4, MCH = N / SPLIT;
constexpr float SCL = 0.125f;   // 1/sqrt(64)

__device__ __forceinline__ unsigned short f2bf(float x) {
    __hip_bfloat16 h = __float2bfloat16(x);
    return *reinterpret_cast<unsigned short*>(&h);
}

// ---------------- projections ----------------
// q[n][d] = sum_k in[n][k] * w[d][k] + bias[d]; writes row-major bf16 qb and
// transposed bf16 qt ([D][N]).
__global__ __launch_bounds__(256) void k_proj_x(const float* __restrict__ x,
        const float* __restrict__ w, const float* __restrict__ bias,
        unsigned short* __restrict__ qb, unsigned short* __restrict__ qt) {
    __shared__ float Xs[64][68];
    __shared__ float Ws[64][68];
    __shared__ float Bs[64];
    const int b = blockIdx.y, n0 = blockIdx.x * 64, t = threadIdx.x;
    const float* xp = x + ((size_t)b * N + n0) * D;
    for (int j = t; j < 4096; j += 256) Xs[j >> 6][j & 63] = xp[j];
    for (int j = t; j < 4096; j += 256) Ws[j >> 6][j & 63] = w[j];
    if (t < 64) Bs[t] = bias[t];
    __syncthreads();
    const int d = t & 63, grp = t >> 6;
    float wr[64];
#pragma unroll
    for (int k4 = 0; k4 < 16; ++k4) {
        float4 v = *reinterpret_cast<const float4*>(&Ws[d][k4 * 4]);
        wr[4 * k4 + 0] = v.x; wr[4 * k4 + 1] = v.y;
        wr[4 * k4 + 2] = v.z; wr[4 * k4 + 3] = v.w;
    }
    for (int i = 0; i < 16; ++i) {
        const int r = grp * 16 + i;
        float acc = Bs[d];
#pragma unroll
        for (int k4 = 0; k4 < 16; ++k4) {
            float4 xv = *reinterpret_cast<const float4*>(&Xs[r][k4 * 4]);
            acc += xv.x * wr[4 * k4] + xv.y * wr[4 * k4 + 1] +
                   xv.z * wr[4 * k4 + 2] + xv.w * wr[4 * k4 + 3];
        }
        qb[((size_t)b * N + n0 + r) * D + d] = f2bf(acc);
        qt[((size_t)b * D + d) * N + n0 + r] = f2bf(acc);
    }
}

// y is (B, D, H*W); token m reads column m: q2[m][d] = sum_k y[b][k][m]*w2[d][k]+b2[d]
__global__ __launch_bounds__(256) void k_proj_y(const float* __restrict__ y,
        const float* __restrict__ w, const float* __restrict__ bias,
        unsigned short* __restrict__ qb, unsigned short* __restrict__ qt) {
    __shared__ float Ys[64][68];   // [m_local][k]
    __shared__ float Ws[64][68];
    __shared__ float Bs[64];
    const int b = blockIdx.y, m0 = blockIdx.x * 64, t = threadIdx.x;
    const float* yp = y + (size_t)b * D * N;
    for (int j = t; j < 4096; j += 256) {
        int k = j >> 6, mm = j & 63;
        Ys[mm][k] = yp[(size_t)k * N + m0 + mm];
    }
    for (int j = t; j < 4096; j += 256) Ws[j >> 6][j & 63] = w[j];
    if (t < 64) Bs[t] = bias[t];
    __syncthreads();
    const int d = t & 63, grp = t >> 6;
    float wr[64];
#pragma unroll
    for (int k4 = 0; k4 < 16; ++k4) {
        float4 v = *reinterpret_cast<const float4*>(&Ws[d][k4 * 4]);
        wr[4 * k4 + 0] = v.x; wr[4 * k4 + 1] = v.y;
        wr[4 * k4 + 2] = v.z; wr[4 * k4 + 3] = v.w;
    }
    for (int i = 0; i < 16; ++i) {
        const int r = grp * 16 + i;
        float acc = Bs[d];
#pragma unroll
        for (int k4 = 0; k4 < 16; ++k4) {
            float4 xv = *reinterpret_cast<const float4*>(&Ys[r][k4 * 4]);
            acc += xv.x * wr[4 * k4] + xv.y * wr[4 * k4 + 1] +
                   xv.z * wr[4 * k4 + 2] + xv.w * wr[4 * k4 + 3];
        }
        qb[((size_t)b * N + m0 + r) * D + d] = f2bf(acc);
        qt[((size_t)b * D + d) * N + m0 + r] = f2bf(acc);
    }
}

// ---------------- pass 1: rows (flash + v2 partials) ----------------
// Each wave: 32 q1-rows, m-range [sp*MCH, (sp+1)*MCH). Online softmax with
// defer-max (THR=8). Writes unnormalized v2 partial, per-row (max, sumexp).
__global__ __launch_bounds__(256) void k_attn_v2(
        const unsigned short* __restrict__ q1b, const unsigned short* __restrict__ q2b,
        const unsigned short* __restrict__ q2t,
        float* __restrict__ v2p, float* __restrict__ smaxp, float* __restrict__ ssump) {
    __shared__ unsigned short stile[4][2][16][32];   // per-wave exp tiles
    const int b = blockIdx.z, sp = blockIdx.y;
    const int w = threadIdx.x >> 6, lane = threadIdx.x & 63;
    const int g = lane >> 4, c = lane & 15;
    const int nb = blockIdx.x * 128 + w * 32;
    const int m_lo = sp * MCH;

    s8v a[2][2];
#pragma unroll
    for (int rt = 0; rt < 2; ++rt) {
        const unsigned short* p = q1b + ((size_t)b * N + nb + rt * 16 + c) * D + 8 * g;
        a[rt][0] = *reinterpret_cast<const s8v*>(p);
        a[rt][1] = *reinterpret_cast<const s8v*>(p + 32);
    }
    f4v accO[2][4] = {};
    float rmax[2][4], rsum[2][4];
#pragma unroll
    for (int rt = 0; rt < 2; ++rt)
#pragma unroll
        for (int r = 0; r < 4; ++r) { rmax[rt][r] = -3.0e38f; rsum[rt][r] = 0.f; }

    for (int m0 = m_lo; m0 < m_lo + MCH; m0 += 32) {
        const unsigned short* pb0 = q2b + ((size_t)b * N + m0 + c) * D + 8 * g;
        s8v b00 = *reinterpret_cast<const s8v*>(pb0);
        s8v b01 = *reinterpret_cast<const s8v*>(pb0 + 32);
        s8v b10 = *reinterpret_cast<const s8v*>(pb0 + 16 * D);
        s8v b11 = *reinterpret_cast<const s8v*>(pb0 + 16 * D + 32);
        float v[2][2][4];
#pragma unroll
        for (int rt = 0; rt < 2; ++rt) {
            f4v acc0 = {}, acc1 = {};
            acc0 = __builtin_amdgcn_mfma_f32_16x16x32_bf16(a[rt][0], b00, acc0, 0, 0, 0);
            acc0 = __builtin_amdgcn_mfma_f32_16x16x32_bf16(a[rt][1], b01, acc0, 0, 0, 0);
            acc1 = __builtin_amdgcn_mfma_f32_16x16x32_bf16(a[rt][0], b10, acc1, 0, 0, 0);
            acc1 = __builtin_amdgcn_mfma_f32_16x16x32_bf16(a[rt][1], b11, acc1, 0, 0, 0);
#pragma unroll
            for (int r = 0; r < 4; ++r) { v[rt][0][r] = acc0[r] * SCL; v[rt][1][r] = acc1[r] * SCL; }
        }
        bool okp = true;
#pragma unroll
        for (int rt = 0; rt < 2; ++rt)
#pragma unroll
            for (int r = 0; r < 4; ++r)
                okp = okp && (v[rt][0][r] <= rmax[rt][r] + 8.f) &&
                             (v[rt][1][r] <= rmax[rt][r] + 8.f);
        if (!__all((int)okp)) {
#pragma unroll
            for (int rt = 0; rt < 2; ++rt)
#pragma unroll
                for (int r = 0; r < 4; ++r) {
                    float tm = fmaxf(v[rt][0][r], v[rt][1][r]);
                    tm = fmaxf(tm, __shfl_xor(tm, 1));
                    tm = fmaxf(tm, __shfl_xor(tm, 2));
                    tm = fmaxf(tm, __shfl_xor(tm, 4));
                    tm = fmaxf(tm, __shfl_xor(tm, 8));
                    float nm = fmaxf(rmax[rt][r], tm);
                    float f = __expf(rmax[rt][r] - nm);
                    rsum[rt][r] *= f;
#pragma unroll
                    for (int dc = 0; dc < 4; ++dc) accO[rt][dc][r] *= f;
                    rmax[rt][r] = nm;
                }
        }
#pragma unroll
        for (int rt = 0; rt < 2; ++rt)
#pragma unroll
            for (int r = 0; r < 4; ++r) {
                float e0 = __expf(v[rt][0][r] - rmax[rt][r]);
                float e1 = __expf(v[rt][1][r] - rmax[rt][r]);
                rsum[rt][r] += e0 + e1;
                stile[w][rt][4 * g + r][c] = f2bf(e0);
                stile[w][rt][4 * g + r][16 + c] = f2bf(e1);
            }
        asm volatile("s_waitcnt lgkmcnt(0)" ::: "memory");
        s8v pa0 = *reinterpret_cast<const s8v*>(&stile[w][0][c][8 * g]);
        s8v pa1 = *reinterpret_cast<const s8v*>(&stile[w][1][c][8 * g]);
#pragma unroll
        for (int dc = 0; dc < 4; ++dc) {
            const unsigned short* pq = q2t + ((size_t)b * D + dc * 16 + c) * N + m0 + 8 * g;
            s8v pb = *reinterpret_cast<const s8v*>(pq);
            accO[0][dc] = __builtin_amdgcn_mfma_f32_16x16x32_bf16(pa0, pb, accO[0][dc], 0, 0, 0);
            accO[1][dc] = __builtin_amdgcn_mfma_f32_16x16x32_bf16(pa1, pb, accO[1][dc], 0, 0, 0);
        }
    }
#pragma unroll
    for (int rt = 0; rt < 2; ++rt)
#pragma unroll
        for (int r = 0; r < 4; ++r) {
            float s = rsum[rt][r];
            s += __shfl_xor(s, 1); s += __shfl_xor(s, 2);
            s += __shfl_xor(s, 4); s += __shfl_xor(s, 8);
            rsum[rt][r] = s;
        }
    const size_t obase = ((size_t)sp * B + b) * N;
#pragma unroll
    for (int rt = 0; rt < 2; ++rt)
#pragma unroll
        for (int dc = 0; dc < 4; ++dc)
#pragma unroll
            for (int r = 0; r < 4; ++r) {
                int n = nb + rt * 16 + 4 * g + r;
                v2p[(obase + n) * D + dc * 16 + c] = accO[rt][dc][r];
            }
    if (c == 0) {
#pragma unroll
        for (int rt = 0; rt < 2; ++rt)
#pragma unroll
            for (int r = 0; r < 4; ++r) {
                int n = nb + rt * 16 + 4 * g + r;
                smaxp[obase + n] = rmax[rt][r];
                ssump[obase + n] = rsum[rt][r];
            }
    }
}

// combine v2 partials; emit off[n] = M + log(S) for pass 2
__global__ __launch_bounds__(256) void k_comb_v2(const float* __restrict__ v2p,
        const float* __restrict__ smaxp, const float* __restrict__ ssump,
        float* __restrict__ out, float* __restrict__ off) {
    const int t = blockIdx.x * 256 + threadIdx.x;   // over B*N*D
    const int d = t & 63, bn = t >> 6;
    float sm[SPLIT], M = -3.0e38f;
#pragma unroll
    for (int s = 0; s < SPLIT; ++s) { sm[s] = smaxp[(size_t)s * B * N + bn]; M = fmaxf(M, sm[s]); }
    float S = 0.f, wgt[SPLIT];
#pragma unroll
    for (int s = 0; s < SPLIT; ++s) { wgt[s] = __expf(sm[s] - M); S += wgt[s] * ssump[(size_t)s * B * N + bn]; }
    const float inv = 1.0f / S;
    float acc = 0.f;
#pragma unroll
    for (int s = 0; s < SPLIT; ++s) acc += wgt[s] * v2p[((size_t)s * B * N + bn) * D + d];
    out[(size_t)bn * D + d] = acc * inv;
    if (d == 0) off[bn] = M + __logf(S);
}

// ---------------- pass 2: columns (v1 partials) ----------------
// Each wave: 32 token-rows m (from q2), n-range split; score recomputed exactly
// as exp(attn^T - off[n]). Stores v1 partial in [s][b][d][m] layout.
__global__ __launch_bounds__(256) void k_attn_v1(
        const unsigned short* __restrict__ q2b, const unsigned short* __restrict__ q1b,
        const unsigned short* __restrict__ q1t, const float* __restrict__ off,
        float* __restrict__ v1p) {
    __shared__ unsigned short stile[4][2][16][32];
    const int b = blockIdx.z, sp = blockIdx.y;
    const int w = threadIdx.x >> 6, lane = threadIdx.x & 63;
    const int g = lane >> 4, c = lane & 15;
    const int mb = blockIdx.x * 128 + w * 32;
    const int n_lo = sp * MCH;
    const float* offb = off + (size_t)b * N;

    s8v a[2][2];
#pragma unroll
    for (int rt = 0; rt < 2; ++rt) {
        const unsigned short* p = q2b + ((size_t)b * N + mb + rt * 16 + c) * D + 8 * g;
        a[rt][0] = *reinterpret_cast<const s8v*>(p);
        a[rt][1] = *reinterpret_cast<const s8v*>(p + 32);
    }
    f4v accO[2][4] = {};

    for (int n0 = n_lo; n0 < n_lo + MCH; n0 += 32) {
        const unsigned short* pb0 = q1b + ((size_t)b * N + n0 + c) * D + 8 * g;
        s8v b00 = *reinterpret_cast<const s8v*>(pb0);
        s8v b01 = *reinterpret_cast<const s8v*>(pb0 + 32);
        s8v b10 = *reinterpret_cast<const s8v*>(pb0 + 16 * D);
        s8v b11 = *reinterpret_cast<const s8v*>(pb0 + 16 * D + 32);
        const float o0 = offb[n0 + c], o1 = offb[n0 + 16 + c];
#pragma unroll
        for (int rt = 0; rt < 2; ++rt) {
            f4v acc0 = {}, acc1 = {};
            acc0 = __builtin_amdgcn_mfma_f32_16x16x32_bf16(a[rt][0], b00, acc0, 0, 0, 0);
            acc0 = __builtin_amdgcn_mfma_f32_16x16x32_bf16(a[rt][1], b01, acc0, 0, 0, 0);
            acc1 = __builtin_amdgcn_mfma_f32_16x16x32_bf16(a[rt][0], b10, acc1, 0, 0, 0);
            acc1 = __builtin_amdgcn_mfma_f32_16x16x32_bf16(a[rt][1], b11, acc1, 0, 0, 0);
#pragma unroll
            for (int r = 0; r < 4; ++r) {
                float e0 = __expf(acc0[r] * SCL - o0);
                float e1 = __expf(acc1[r] * SCL - o1);
                stile[w][rt][4 * g + r][c] = f2bf(e0);
                stile[w][rt][4 * g + r][16 + c] = f2bf(e1);
            }
        }
        asm volatile("s_waitcnt lgkmcnt(0)" ::: "memory");
        s8v pa0 = *reinterpret_cast<const s8v*>(&stile[w][0][c][8 * g]);
        s8v pa1 = *reinterpret_cast<const s8v*>(&stile[w][1][c][8 * g]);
#pragma unroll
        for (int dc = 0; dc < 4; ++dc) {
            const unsigned short* pq = q1t + ((size_t)b * D + dc * 16 + c) * N + n0 + 8 * g;
            s8v pb = *reinterpret_cast<const s8v*>(pq);
            accO[0][dc] = __builtin_amdgcn_mfma_f32_16x16x32_bf16(pa0, pb, accO[0][dc], 0, 0, 0);
            accO[1][dc] = __builtin_amdgcn_mfma_f32_16x16x32_bf16(pa1, pb, accO[1][dc], 0, 0, 0);
        }
    }
    // v1p[sp][b][d][m]: lane's 4 acc entries are consecutive m -> float4 store
#pragma unroll
    for (int rt = 0; rt < 2; ++rt)
#pragma unroll
        for (int dc = 0; dc < 4; ++dc) {
            const int d = dc * 16 + c;
            size_t base = (((size_t)sp * B + b) * D + d) * N + mb + rt * 16 + 4 * g;
            *reinterpret_cast<f4v*>(&v1p[base]) = accO[rt][dc];
        }
}

__global__ __launch_bounds__(256) void k_comb_v1(const float* __restrict__ v1p,
        float* __restrict__ out2) {
    const size_t t = (size_t)blockIdx.x * 256 + threadIdx.x;   // over B*D*N
    float acc = 0.f;
#pragma unroll
    for (int s = 0; s < SPLIT; ++s) acc += v1p[(size_t)s * B * D * N + t];
    out2[t] = acc;
}

extern "C" void kernel_launch(void* const* d_in, const int* in_sizes, int n_in,
                              void* d_out, int out_size, void* d_ws, size_t ws_size,
                              hipStream_t stream) {
    const float* x  = (const float*)d_in[0];
    const float* y  = (const float*)d_in[1];
    const float* w1 = (const float*)d_in[2];
    const float* b1 = (const float*)d_in[3];
    const float* w2 = (const float*)d_in[4];
    const float* b2 = (const float*)d_in[5];
    float* out = (float*)d_out;

    char* ws = (char*)d_ws;
    const size_t QE = (size_t)B * N * D;          // elements per q matrix
    unsigned short* q1b = (unsigned short*)ws;
    unsigned short* q2b = q1b + QE;
    unsigned short* q1t = q2b + QE;
    unsigned short* q2t = q1t + QE;
    float* fb   = (float*)(ws + QE * 4 * sizeof(unsigned short));
    float* off  = fb;
    float* smax = off + (size_t)B * N;
    float* ssum = smax + (size_t)SPLIT * B * N;
    float* v2p  = ssum + (size_t)SPLIT * B * N;
    float* v1p  = v2p + (size_t)SPLIT * QE;

    dim3 blk(256);
    k_proj_x<<<dim3(N / 64, B), blk, 0, stream>>>(x, w1, b1, q1b, q1t);
    k_proj_y<<<dim3(N / 64, B), blk, 0, stream>>>(y, w2, b2, q2b, q2t);
    k_attn_v2<<<dim3(N / 128, SPLIT, B), blk, 0, stream>>>(q1b, q2b, q2t, v2p, smax, ssum);
    k_comb_v2<<<dim3(B * N * D / 256), blk, 0, stream>>>(v2p, smax, ssum, out, off);
    k_attn_v1<<<dim3(N / 128, SPLIT, B), blk, 0, stream>>>(q2b, q1b, q1t, off, v1p);
    k_comb_v1<<<dim3(B * D * N / 256), blk, 0, stream>>>(v1p, out + QE);
}